// Round 2
// 723.967 us; speedup vs baseline: 1.0525x; 1.0525x over previous
//
#include <hip/hip_runtime.h>

// ---------------------------------------------------------------------------
// Sigmoid attention, MI355X. B=2 N=2048 C=1024 H=16 dh=64.
// Outputs (f32, concat): attn_matrix [2,16,2048,2048], atv [2,2048,1024],
//                        proj [2,2048,1024].
// R2: keep R1's verified pieces (gload_lds+swizzle GEMM staging, S^T attn,
//     float4 NT P-stores, XCD swizzle). PV A-frag goes back through LDS
//     (proven R0 read pattern) but with packed ds_write_b64 of cvt_pk pairs.
//     Middle barrier removed (Pl rows wave-private).
// ---------------------------------------------------------------------------

typedef short short8 __attribute__((ext_vector_type(8)));    // 8 bf16 raw bits
typedef unsigned short ushort8v __attribute__((ext_vector_type(8)));
typedef float f32x4 __attribute__((ext_vector_type(4)));

#define DEV static __device__ __forceinline__

DEV unsigned short f2bf(float f) {          // round-to-nearest-even f32->bf16
  unsigned u = __builtin_bit_cast(unsigned, f);
  u += 0x7FFFu + ((u >> 16) & 1u);
  return (unsigned short)(u >> 16);
}

DEV unsigned cvt_pk_bf16(float lo, float hi) {  // D = {hi<<16 | lo} as bf16
  unsigned r;
  asm("v_cvt_pk_bf16_f32 %0, %1, %2" : "=v"(r) : "v"(lo), "v"(hi));
  return r;
}

DEV void gload_lds16(const void* g, void* l) {  // async 16B/lane global->LDS
  __builtin_amdgcn_global_load_lds(
      (const __attribute__((address_space(1))) unsigned*)g,
      (__attribute__((address_space(3))) unsigned*)l, 16, 0, 0);
}

DEV float sigmoid_from_s(float s) {
  // sigmoid(s*0.125 - 7.625) = 1/(1 + exp2(-0.18033688*s + 11.00054968))
  float e = __builtin_amdgcn_exp2f(__builtin_fmaf(s, -0.18033688f, 11.00054968f));
  return __builtin_amdgcn_rcpf(1.0f + e);
}

// ---------------------------------------------------------------------------
__global__ void cvt_f32_bf16(const float* __restrict__ in,
                             unsigned short* __restrict__ out, int n4) {
  int i = blockIdx.x * blockDim.x + threadIdx.x;
  if (i >= n4) return;
  float4 f = ((const float4*)in)[i];
  ushort4 o;
  o.x = f2bf(f.x); o.y = f2bf(f.y); o.z = f2bf(f.z); o.w = f2bf(f.w);
  ((ushort4*)out)[i] = o;
}

// ---------------------------------------------------------------------------
// C[M,N] = A[M,K] @ B[N,K]^T, bf16 in / f32 acc. 128x128 tile, BK=64,
// 256 threads = 4 waves in 2x2, each wave 64x64 (4x4 MFMA tiles).
// Staging: global_load_lds width=16, linear LDS [128][64], XOR-swizzled
// source chunks (rule 21: linear dest + inverse-swz source + swz on read).
// MODE 0: scatter bf16 into q/k/v [B,H,N,64] sections. MODE 1: f32 row-major.
// (Verified R1: outputs depending on MODE 0 passed.)
template<int MODE>
__global__ __launch_bounds__(256) void gemm_bf16_nt(
    const unsigned short* __restrict__ A, const unsigned short* __restrict__ B,
    unsigned short* __restrict__ outQKV, float* __restrict__ outF,
    int M, int N, int K) {
  __shared__ __align__(16) unsigned short At[128 * 64];
  __shared__ __align__(16) unsigned short Bt[128 * 64];
  const int t = threadIdx.x;
  const int row0 = blockIdx.x * 128, col0 = blockIdx.y * 128;
  const int w = t >> 6, lane = t & 63, lm = lane & 15, quad = lane >> 4;
  const int mb = (w >> 1) * 64, nb = (w & 1) * 64;
  const int sr = w * 32 + (lane >> 3);   // staging row base (+8*ii)
  const int l8 = lane & 7;

  f32x4 acc[4][4];
#pragma unroll
  for (int i = 0; i < 4; i++)
#pragma unroll
    for (int j = 0; j < 4; j++) acc[i][j] = (f32x4)0.0f;

  for (int k0 = 0; k0 < K; k0 += 64) {
#pragma unroll
    for (int ii = 0; ii < 4; ii++) {
      int rg = sr + 8 * ii;
      int cc = l8 ^ (rg & 7);            // inverse-swizzled global 16B chunk
      gload_lds16(&A[(size_t)(row0 + rg) * K + k0 + cc * 8],
                  &At[(w * 32 + 8 * ii) * 64]);
      gload_lds16(&B[(size_t)(col0 + rg) * K + k0 + cc * 8],
                  &Bt[(w * 32 + 8 * ii) * 64]);
    }
    __syncthreads();                     // drains vmcnt -> LDS tiles ready
#pragma unroll
    for (int kc = 0; kc < 2; kc++) {
      short8 af[4], bf[4];
#pragma unroll
      for (int i = 0; i < 4; i++)
        af[i] = *(const short8*)&At[(mb + 16 * i + lm) * 64 +
                                    (((kc << 2) + quad) ^ (lm & 7)) * 8];
#pragma unroll
      for (int j = 0; j < 4; j++)
        bf[j] = *(const short8*)&Bt[(nb + 16 * j + lm) * 64 +
                                    (((kc << 2) + quad) ^ (lm & 7)) * 8];
#pragma unroll
      for (int i = 0; i < 4; i++)
#pragma unroll
        for (int j = 0; j < 4; j++)
          acc[i][j] = __builtin_amdgcn_mfma_f32_16x16x32_bf16(
              af[i], bf[j], acc[i][j], 0, 0, 0);
    }
    __syncthreads();
  }

  // epilogue: C/D layout col=lane&15, row=quad*4+reg
#pragma unroll
  for (int i = 0; i < 4; i++) {
#pragma unroll
    for (int j = 0; j < 4; j++) {
#pragma unroll
      for (int r = 0; r < 4; r++) {
        int rM = row0 + mb + 16 * i + quad * 4 + r;
        int cN = col0 + nb + 16 * j + lm;
        float v = acc[i][j][r];
        if (MODE == 0) {
          // channel cN in [0,3072): s*1024 + h*64 + d ; row rM: b*2048 + n
          int s = cN >> 10, hh = (cN >> 6) & 15, d = cN & 63;
          int b = rM >> 11, nl = rM & 2047;
          outQKV[(size_t)s * 4194304 +
                 ((size_t)((b << 4) + hh) * 2048 + nl) * 64 + d] = f2bf(v);
        } else {
          outF[(size_t)rM * N + cN] = v;
        }
      }
    }
  }
}

// ---------------------------------------------------------------------------
// Fused attention: one block per (b,h,q-tile of 128 rows). 4 waves, each owns
// 32 q-rows. Per 128-wide k-tile: S^T = mfma(K,Q) -> sigmoid -> float4 NT
// store of P -> ds_write_b64 packed bf16 pairs to wave-private Pl rows ->
// PV accumulate (R0-proven read pattern). No middle barrier.
__global__ __launch_bounds__(256) void attn_sigmoid(
    const unsigned short* __restrict__ Q, const unsigned short* __restrict__ Kk,
    const unsigned short* __restrict__ V, float* __restrict__ Pout,
    float* __restrict__ atvF, unsigned short* __restrict__ atvB) {
  __shared__ __align__(16) unsigned short Kt[128 * 64];   // K-tile, swizzled
  __shared__ __align__(16) unsigned short Vt[64 * 136];   // V^T [64][128]+pad
  __shared__ __align__(16) unsigned short Pl[128 * 136];  // P bf16 [128][128]+pad

  const int t = threadIdx.x;
  // bijective XCD swizzle (512 blocks % 8 == 0): each XCD gets 4 contiguous
  // (b,h) groups -> the 16 q-tiles sharing one head's K/V hit one L2.
  const int swz = (blockIdx.x & 7) * 64 + (blockIdx.x >> 3);
  const int qt = swz & 15, bh = swz >> 4;
  const int b = bh >> 4, h = bh & 15;
  const int q0 = qt * 128;
  const int w = t >> 6, lane = t & 63, lm = lane & 15, quad = lane >> 4;
  const int sr = w * 32 + (lane >> 3), l8 = lane & 7;

  const unsigned short* qh = Q + (size_t)bh * 2048 * 64;
  const unsigned short* kh = Kk + (size_t)bh * 2048 * 64;
  const unsigned short* vh = V + (size_t)bh * 2048 * 64;
  float* pbase = Pout + (size_t)bh * 2048 * 2048;

  // Q fragments live in registers for the whole kernel (B-operand of S^T)
  short8 qf[2][2];
#pragma unroll
  for (int i = 0; i < 2; i++)
#pragma unroll
    for (int kc = 0; kc < 2; kc++)
      qf[i][kc] = *(const short8*)&qh[(size_t)(q0 + w * 32 + 16 * i + lm) * 64 +
                                      kc * 32 + quad * 8];

  f32x4 oacc[2][4];
#pragma unroll
  for (int i = 0; i < 2; i++)
#pragma unroll
    for (int n = 0; n < 4; n++) oacc[i][n] = (f32x4)0.0f;

  for (int kt = 0; kt < 16; kt++) {
    const int k0 = kt * 128;
    // ---- stage K-tile via global_load_lds, XOR-swizzled source ----
#pragma unroll
    for (int ii = 0; ii < 4; ii++) {
      int rg = sr + 8 * ii;
      int cc = l8 ^ (rg & 7);
      gload_lds16(&kh[(size_t)(k0 + rg) * 64 + cc * 8],
                  &Kt[(w * 32 + 8 * ii) * 64]);
    }
    // ---- stage V-tile transposed: Vt[d][k] ----
    {
      int r = t & 127, cb = t >> 7;
#pragma unroll
      for (int i = 0; i < 4; i++) {
        int cc2 = cb + 2 * i;  // chunk of 8 d's
        ushort8v vv = *(const ushort8v*)&vh[(size_t)(k0 + r) * 64 + cc2 * 8];
#pragma unroll
        for (int l = 0; l < 8; l++) Vt[(cc2 * 8 + l) * 136 + r] = vv[l];
      }
    }
    __syncthreads();

    // ---- S^T = K Q^T : acc row = k (quad*4+reg), col = q (lm) ----
    f32x4 sacc[2][8];
#pragma unroll
    for (int i = 0; i < 2; i++)
#pragma unroll
      for (int j = 0; j < 8; j++) sacc[i][j] = (f32x4)0.0f;
#pragma unroll
    for (int kc = 0; kc < 2; kc++) {
      short8 bk[8];
#pragma unroll
      for (int j = 0; j < 8; j++)
        bk[j] = *(const short8*)&Kt[(16 * j + lm) * 64 +
                                    (((kc << 2) + quad) ^ (lm & 7)) * 8];
#pragma unroll
      for (int i = 0; i < 2; i++)
#pragma unroll
        for (int j = 0; j < 8; j++)
          sacc[i][j] = __builtin_amdgcn_mfma_f32_16x16x32_bf16(
              bk[j], qf[i][kc], sacc[i][j], 0, 0, 0);
    }

    // ---- sigmoid; float4 NT store of P (k-contiguous in S^T layout);
    //      packed bf16 pair -> one ds_write_b64 into wave-private Pl row ----
#pragma unroll
    for (int i = 0; i < 2; i++) {
#pragma unroll
      for (int j = 0; j < 8; j++) {
        f32x4 p;
#pragma unroll
        for (int r = 0; r < 4; r++) p[r] = sigmoid_from_s(sacc[i][j][r]);
        __builtin_nontemporal_store(
            p, (f32x4*)&pbase[(size_t)(q0 + w * 32 + 16 * i + lm) * 2048 +
                              k0 + 16 * j + quad * 4]);
        uint2 pw;
        pw.x = cvt_pk_bf16(p[0], p[1]);  // k = 16j+4*quad + {0,1}
        pw.y = cvt_pk_bf16(p[2], p[3]);  // k = 16j+4*quad + {2,3}
        *(uint2*)&Pl[(w * 32 + 16 * i + lm) * 136 + 16 * j + quad * 4] = pw;
      }
    }
    // no barrier: Pl rows are wave-private; within-wave lgkmcnt orders
    // ds_write -> ds_read (whole-wave visibility).

    // ---- O += P V  (A from private Pl rows, B from Vt; R0-proven) ----
#pragma unroll
    for (int kc = 0; kc < 4; kc++) {
      short8 ap[2], bv[4];
#pragma unroll
      for (int i = 0; i < 2; i++)
        ap[i] = *(const short8*)&Pl[(w * 32 + 16 * i + lm) * 136 + kc * 32 +
                                    quad * 8];
#pragma unroll
      for (int n = 0; n < 4; n++)
        bv[n] = *(const short8*)&Vt[(16 * n + lm) * 136 + kc * 32 + quad * 8];
#pragma unroll
      for (int i = 0; i < 2; i++)
#pragma unroll
        for (int n = 0; n < 4; n++)
          oacc[i][n] = __builtin_amdgcn_mfma_f32_16x16x32_bf16(
              ap[i], bv[n], oacc[i][n], 0, 0, 0);
    }
    __syncthreads();   // protect Kt/Vt overwrite; drains NT P-stores here
  }

  // ---- epilogue: atv [B,N,H*64] f32 + bf16 copy for proj GEMM ----
#pragma unroll
  for (int i = 0; i < 2; i++) {
#pragma unroll
    for (int n = 0; n < 4; n++) {
#pragma unroll
      for (int r = 0; r < 4; r++) {
        int grow = q0 + w * 32 + 16 * i + quad * 4 + r;
        int gcol = h * 64 + 16 * n + lm;
        size_t idx = ((size_t)(b * 2048 + grow)) * 1024 + gcol;
        float v = oacc[i][n][r];
        atvF[idx] = v;
        atvB[idx] = f2bf(v);
      }
    }
  }
}

// ---------------------------------------------------------------------------
extern "C" void kernel_launch(void* const* d_in, const int* in_sizes, int n_in,
                              void* d_out, int out_size, void* d_ws,
                              size_t ws_size, hipStream_t stream) {
  const float* x = (const float*)d_in[0];        // [2,2048,1024]
  const float* w_qkv = (const float*)d_in[1];    // [3072,1024]
  const float* w_proj = (const float*)d_in[2];   // [1024,1024]

  float* Pout = (float*)d_out;                         // 134217728 floats
  float* atvOut = (float*)d_out + 134217728;           // 4194304 floats
  float* projOut = (float*)d_out + 138412032;          // 4194304 floats

  unsigned char* ws = (unsigned char*)d_ws;
  unsigned short* xbf = (unsigned short*)(ws + 0);             // 8 MB
  unsigned short* wqkvbf = (unsigned short*)(ws + 8388608);    // 6 MB
  unsigned short* wprojbf = (unsigned short*)(ws + 14680064);  // 2 MB
  unsigned short* qb = (unsigned short*)(ws + 16777216);       // 8 MB
  unsigned short* kb = (unsigned short*)(ws + 25165824);       // 8 MB
  unsigned short* vb = (unsigned short*)(ws + 33554432);       // 8 MB
  unsigned short* atvbf = (unsigned short*)(ws + 41943040);    // 8 MB

  cvt_f32_bf16<<<4096, 256, 0, stream>>>(x, xbf, 1048576);
  cvt_f32_bf16<<<3072, 256, 0, stream>>>(w_qkv, wqkvbf, 786432);
  cvt_f32_bf16<<<1024, 256, 0, stream>>>(w_proj, wprojbf, 262144);

  gemm_bf16_nt<0><<<dim3(32, 24), 256, 0, stream>>>(xbf, wqkvbf, qb, nullptr,
                                                    4096, 3072, 1024);

  attn_sigmoid<<<512, 256, 0, stream>>>(qb, kb, vb, Pout, atvOut, atvbf);

  gemm_bf16_nt<1><<<dim3(32, 8), 256, 0, stream>>>(atvbf, wprojbf, nullptr,
                                                   projOut, 4096, 1024, 1024);
}